// Round 20
// baseline (213.419 us; speedup 1.0000x reference)
//
#include <hip/hip_runtime.h>

#define HD 1024
#define FD 2816
#define NE 8
#define NT 1024
#define NSLOT (NT * 2)

typedef short short8 __attribute__((ext_vector_type(8)));
typedef unsigned u32x4 __attribute__((ext_vector_type(4)));
typedef unsigned u32x2 __attribute__((ext_vector_type(2)));
typedef float f32x4 __attribute__((ext_vector_type(4)));
typedef float f32x16 __attribute__((ext_vector_type(16)));

typedef __attribute__((address_space(3))) unsigned lds_u32;
typedef __attribute__((address_space(1))) const unsigned glb_u32;

#define WAITV(N) asm volatile("s_waitcnt vmcnt(" #N ") lgkmcnt(0)" ::: "memory")
#define BARRIER() do { __builtin_amdgcn_s_barrier(); __builtin_amdgcn_sched_barrier(0); } while (0)
#define SB() __builtin_amdgcn_sched_barrier(0)

__device__ __forceinline__ void glds16(const void* g, void* l) {
  __builtin_amdgcn_global_load_lds((glb_u32*)g, (lds_u32*)l, 16, 0, 0);
}

__device__ __forceinline__ short f2bf(float f) {
  unsigned u = __builtin_bit_cast(unsigned, f);
  u += 0x7FFFu + ((u >> 16) & 1u);   // round-to-nearest-even
  return (short)(u >> 16);
}
__device__ __forceinline__ unsigned cvtpk(float lo, float hi) {
  unsigned r;
  asm("v_cvt_pk_bf16_f32 %0, %1, %2" : "=v"(r) : "v"(lo), "v"(hi));
  return r;
}
__device__ __forceinline__ int imin(int a, int b) { return a < b ? a : b; }

// ---------------- router ----------------------------------------------------
__global__ void router_kernel(const float* __restrict__ x,
                              const float* __restrict__ rw,
                              int* __restrict__ counts,
                              int* __restrict__ tok_i,
                              float* __restrict__ tok_w) {
  const int t = blockIdx.x;
  const int lane = threadIdx.x;
  const float* px = x + (size_t)t * HD;
  float acc[NE];
#pragma unroll
  for (int e = 0; e < NE; e++) acc[e] = 0.f;
  for (int h = lane; h < HD; h += 64) {
    float xv = px[h];
#pragma unroll
    for (int e = 0; e < NE; e++) acc[e] += xv * rw[e * HD + h];
  }
#pragma unroll
  for (int e = 0; e < NE; e++) {
#pragma unroll
    for (int off = 32; off > 0; off >>= 1)
      acc[e] += __shfl_xor(acc[e], off, 64);
  }
  if (lane == 0) {
    float mx = acc[0];
#pragma unroll
    for (int e = 1; e < NE; e++) mx = fmaxf(mx, acc[e]);
    float ex[NE];
#pragma unroll
    for (int e = 0; e < NE; e++) ex[e] = __expf(acc[e] - mx);
    int i1 = 0;
#pragma unroll
    for (int e = 1; e < NE; e++) if (ex[e] > ex[i1]) i1 = e;
    int i2 = (i1 == 0) ? 1 : 0;
#pragma unroll
    for (int e = 0; e < NE; e++) if (e != i1 && ex[e] > ex[i2]) i2 = e;
    float inv = 1.f / (ex[i1] + ex[i2]);
    tok_i[t * 2 + 0] = i1; tok_w[t * 2 + 0] = ex[i1] * inv;
    tok_i[t * 2 + 1] = i2; tok_w[t * 2 + 1] = ex[i2] * inv;
    atomicAdd(&counts[i1], 1);
    atomicAdd(&counts[i2], 1);
  }
}

// ---------------- fused scan+fill (one block) -------------------------------
__global__ void scanfill_kernel(const int* __restrict__ counts,
                                const int* __restrict__ tok_i,
                                const float* __restrict__ tok_w,
                                int* __restrict__ bases,
                                int* __restrict__ slot_token,
                                float* __restrict__ slot_w) {
  __shared__ int cur[NE];
  const int t = threadIdx.x;
  if (t == 0) {
    int s = 0;
    for (int e = 0; e < NE; e++) { bases[e] = s; cur[e] = s; s += counts[e]; }
    bases[NE] = s;
  }
  __syncthreads();
#pragma unroll
  for (int k = 0; k < 2; k++) {
    int e = tok_i[t * 2 + k];
    int pos = atomicAdd(&cur[e], 1);
    slot_token[pos] = t;
    slot_w[pos] = tok_w[t * 2 + k];
  }
}

// ---------------- pack: LDS-bounce, NONTEMPORAL panel stores ----------------
__device__ __forceinline__ void pack_block(const float* __restrict__ W,
                                           short* __restrict__ P, int K, int N,
                                           int f0, int kt, int e, int tid,
                                           char* smem) {
  const int KT = K >> 5;
  const int lane = tid & 63, w = tid >> 6;
  const float* src = W + (size_t)e * K * N + (size_t)(kt * 32 + w * 8) * N +
                     f0 + lane * 4;
  f32x4 x0 = *(const f32x4*)(src);
  f32x4 x1 = *(const f32x4*)(src + (size_t)N);
  f32x4 x2 = *(const f32x4*)(src + (size_t)2 * N);
  f32x4 x3 = *(const f32x4*)(src + (size_t)3 * N);
  f32x4 x4 = *(const f32x4*)(src + (size_t)4 * N);
  f32x4 x5 = *(const f32x4*)(src + (size_t)5 * N);
  f32x4 x6 = *(const f32x4*)(src + (size_t)6 * N);
  f32x4 x7 = *(const f32x4*)(src + (size_t)7 * N);
  unsigned* Lb = (unsigned*)(smem + w * 4608);
#pragma unroll
  for (int j = 0; j < 4; j++) {
    u32x4 c;
    c[0] = cvtpk(x0[j], x1[j]);
    c[1] = cvtpk(x2[j], x3[j]);
    c[2] = cvtpk(x4[j], x5[j]);
    c[3] = cvtpk(x6[j], x7[j]);
    int ch = 4 * lane + j;
    *(u32x4*)(Lb + (ch + (ch >> 3)) * 4) = c;
  }
  asm volatile("s_waitcnt lgkmcnt(0)" ::: "memory");
  SB();
  short* dstb = P + (((size_t)(e * KT + kt) * 4 + w) * N + f0) * 8;
#pragma unroll
  for (int j = 0; j < 4; j++) {
    int ch = j * 64 + lane;
    u32x4 c = *(const u32x4*)(Lb + (ch + (ch >> 3)) * 4);
    __builtin_nontemporal_store(c, (u32x4*)(dstb + (size_t)ch * 8));
  }
}

// ---------------- K3: pack gate+up  UNION  gather (r13 topology) ------------
__global__ __launch_bounds__(256, 4) void pack_gu_gather_kernel(
    const float* __restrict__ gw, const float* __restrict__ uw,
    short* __restrict__ Pg, short* __restrict__ Pu,
    const float* __restrict__ x, const int* __restrict__ slot_token,
    short* __restrict__ xg) {
  __shared__ char smem[18432];
  const int bid = blockIdx.x;
  const int tid = threadIdx.x;
  if (bid < 5632) {   // 11 x 32 x 16 pack blocks
    const int f0 = (bid % 11) * 256;
    const int kt = (bid / 11) % 32;
    const int ez = bid / 352;
    pack_block(ez < NE ? gw : uw, ez < NE ? Pg : Pu, HD, FD, f0, kt, ez & 7,
               tid, smem);
  } else {            // 2048 gather blocks
    const int slot = bid - 5632;
    const int tok = slot_token[slot];
    f32x4 v = *(const f32x4*)(x + (size_t)tok * HD + tid * 4);
    u32x2 s;
    s[0] = cvtpk(v[0], v[1]);
    s[1] = cvtpk(v[2], v[3]);
    *(u32x2*)&xg[(size_t)slot * HD + tid * 4] = s;
  }
}

// ---------------- K4: fused gate+up GEMM  UNION  pack down (r13) ------------

#define G_STAGE(S, T) do {                                           \
    glds16(asrc0 + (T) * 32, &As[S][wid * 512]);                     \
    glds16(asrc1 + (T) * 32, &As[S][2048 + wid * 512]);              \
    glds16(bgsrc + (size_t)(T) * 90112, &Bg[S][wid * 512]);          \
    glds16(busrc + (size_t)(T) * 90112, &Bu[S][wid * 512]);          \
  } while (0)

#define G_COMPUTE(S) do {                                                     \
    _Pragma("unroll")                                                         \
    for (int ks = 0; ks < 2; ks++) {                                          \
      const int oct = ks * 2 + l5;                                            \
      short8 a0, a1, bg, bu;                                                  \
      { int r = wm * 64 + l31, p = r >> 1;                                    \
        a0 = *(const short8*)&As[S][p * 64 +                                  \
              ((((r & 1) << 2) | oct) ^ (p & 7)) * 8]; }                      \
      { int r = wm * 64 + 32 + l31, p = r >> 1;                               \
        a1 = *(const short8*)&As[S][p * 64 +                                  \
              ((((r & 1) << 2) | oct) ^ (p & 7)) * 8]; }                      \
      { int n = wn * 32 + l31, pn = n >> 1;                                   \
        int off = pn * 64 + ((((n & 1) << 2) | oct) ^ (pn & 7)) * 8;          \
        bg = *(const short8*)&Bg[S][off];                                     \
        bu = *(const short8*)&Bu[S][off]; }                                   \
      accG0 = __builtin_amdgcn_mfma_f32_32x32x16_bf16(a0, bg, accG0, 0, 0, 0);\
      accU0 = __builtin_amdgcn_mfma_f32_32x32x16_bf16(a0, bu, accU0, 0, 0, 0);\
      accG1 = __builtin_amdgcn_mfma_f32_32x32x16_bf16(a1, bg, accG1, 0, 0, 0);\
      accU1 = __builtin_amdgcn_mfma_f32_32x32x16_bf16(a1, bu, accU1, 0, 0, 0);\
    }                                                                         \
  } while (0)

#define G_ITER(S, T) do {    \
    G_COMPUTE(S);            \
    BARRIER();               \
    G_STAGE(S, (T) + 3);     \
    WAITV(8);                \
    BARRIER();               \
  } while (0)

__global__ __launch_bounds__(256, 3) void gemm_gu_packd_kernel(
    const short* __restrict__ xg, const short* __restrict__ Pg,
    const short* __restrict__ Pu, const int* __restrict__ bases,
    short* __restrict__ m_out, const float* __restrict__ dwv,
    short* __restrict__ Pd, int gemmN) {
  __shared__ char smem[49152];
  const int bid = blockIdx.x;
  const int tid = threadIdx.x;

  if (bid >= gemmN) {   // pack-down blocks: 4 x 88 x 8 (single tile each)
    const int pid = bid - gemmN;
    const int f0 = (pid & 3) * 256;
    const int kt = (pid >> 2) % 88;
    const int e = pid / 352;
    pack_block(dwv, Pd, FD, HD, f0, kt, e, tid, smem);
    return;
  }

  const int gx = bid % 352;
  const int e = gx / 44, nt = gx - e * 44;
  const int b0 = bases[e];
  const int ne = bases[e + 1] - b0;
  const int row0 = (bid / 352) * 128;
  if (row0 >= ne) return;
  const int n0 = nt * 64;

  short (*As)[4096] = (short(*)[4096])smem;              // 3 x 8 KB
  short (*Bg)[2048] = (short(*)[2048])(smem + 24576);    // 3 x 4 KB
  short (*Bu)[2048] = (short(*)[2048])(smem + 36864);    // 3 x 4 KB

  const int lane = tid & 63, wid = tid >> 6;
  const int l31 = lane & 31, l5 = lane >> 5;
  const int wm = wid >> 1, wn = wid & 1;

  const short *asrc0, *asrc1;
  {
    int i = tid;
    int p = i >> 3, j = i & 7, v = j ^ (p & 7);
    int r = 2 * p + (v >> 2), c = v & 3;
    asrc0 = xg + (size_t)(b0 + imin(row0 + r, ne - 1)) * HD + c * 8;
    i = 256 + tid;
    p = i >> 3; j = i & 7; v = j ^ (p & 7);
    r = 2 * p + (v >> 2); c = v & 3;
    asrc1 = xg + (size_t)(b0 + imin(row0 + r, ne - 1)) * HD + c * 8;
  }
  const short *bgsrc, *busrc;
  {
    int p = tid >> 3, j = tid & 7, v = j ^ (p & 7);
    int r = 2 * p + (v >> 2), c = v & 3;
    size_t off = ((size_t)(e * 32 * 4 + c)) * (FD * 8) + (size_t)(n0 + r) * 8;
    bgsrc = Pg + off;
    busrc = Pu + off;
  }

  f32x16 accG0 = (f32x16)0.f, accG1 = (f32x16)0.f;
  f32x16 accU0 = (f32x16)0.f, accU1 = (f32x16)0.f;

  G_STAGE(0, 0); G_STAGE(1, 1); G_STAGE(2, 2);
  WAITV(8);
  BARRIER();

  for (int t = 0; t < 27; t += 3) {   // NTL = 32
    G_ITER(0, t);
    G_ITER(1, t + 1);
    G_ITER(2, t + 2);
  }
  G_ITER(0, 27);
  G_ITER(1, 28);
  G_COMPUTE(2);            // t=29
  WAITV(4); BARRIER();
  G_COMPUTE(0);            // t=30
  WAITV(0); BARRIER();
  G_COMPUTE(1);            // t=31

#pragma unroll
  for (int q = 0; q < 16; q++) {
    int rb_ = (q & 3) + 8 * (q >> 2) + 4 * l5;
    {
      int r = row0 + wm * 64 + rb_;
      if (r < ne) {
        float g = accG0[q], u = accU0[q];
        float mv = (g / (1.f + __expf(-g))) * u;
        m_out[(size_t)(b0 + r) * FD + n0 + wn * 32 + l31] = f2bf(mv);
      }
    }
    {
      int r = row0 + wm * 64 + 32 + rb_;
      if (r < ne) {
        float g = accG1[q], u = accU1[q];
        float mv = (g / (1.f + __expf(-g))) * u;
        m_out[(size_t)(b0 + r) * FD + n0 + wn * 32 + l31] = f2bf(mv);
      }
    }
  }
}

// ============ down grouped GEMM (BM=64 BN=64 BK=64, all-glds 3-deep) ========

#define D_STAGE(S, T) do {                                           \
    glds16(asrcA0 + (T) * 64, &As[S][wid * 512]);                    \
    glds16(asrcA1 + (T) * 64, &As[S][2048 + wid * 512]);             \
    glds16(bsrc0 + (size_t)(T) * 65536, &Bs[S][wid * 512]);          \
    glds16(bsrc1 + (size_t)(T) * 65536, &Bs[S][2048 + wid * 512]);   \
  } while (0)

#define D_COMPUTE(S) do {                                                     \
    _Pragma("unroll")                                                         \
    for (int ks = 0; ks < 4; ks++) {                                          \
      const int sub = ks >> 1, oct = (ks & 1) * 2 + l5;                       \
      short8 a, b;                                                            \
      { int r = wm * 32 + l31, p = r >> 1;                                    \
        a = *(const short8*)&As[S][sub * 2048 + p * 64 +                      \
              ((((r & 1) << 2) | oct) ^ (p & 7)) * 8]; }                      \
      { int n = wn * 32 + l31, pn = n >> 1;                                   \
        b = *(const short8*)&Bs[S][sub * 2048 + pn * 64 +                     \
              ((((n & 1) << 2) | oct) ^ (pn & 7)) * 8]; }                     \
      acc = __builtin_amdgcn_mfma_f32_32x32x16_bf16(a, b, acc, 0, 0, 0);      \
    }                                                                         \
  } while (0)

#define D_ITER(S, T) do {    \
    D_COMPUTE(S);            \
    BARRIER();               \
    D_STAGE(S, (T) + 3);     \
    WAITV(8);                \
    BARRIER();               \
  } while (0)

__global__ __launch_bounds__(256, 3) void down_kernel(
    const short* __restrict__ m_in, const short* __restrict__ Pd,
    const int* __restrict__ bases, const float* __restrict__ slot_w,
    const int* __restrict__ slot_token, float* __restrict__ out) {
  const int bx = blockIdx.x;
  const int e = bx >> 4, nt = bx & 15;
  const int b0 = bases[e];
  const int ne = bases[e + 1] - b0;
  const int row0 = blockIdx.y * 64;
  if (row0 >= ne) return;
  const int n0 = nt * 64;

  __shared__ short As[3][4096];
  __shared__ short Bs[3][4096];

  const int tid = threadIdx.x;
  const int lane = tid & 63, wid = tid >> 6;
  const int l31 = lane & 31, l5 = lane >> 5;
  const int wm = wid >> 1, wn = wid & 1;

  const short *asrcA0, *asrcA1;
  {
    int p = tid >> 3, j = tid & 7, v = j ^ (p & 7);
    int r = 2 * p + (v >> 2), c = v & 3;
    const short* base = m_in + (size_t)(b0 + imin(row0 + r, ne - 1)) * FD;
    asrcA0 = base + c * 8;
    asrcA1 = base + 32 + c * 8;
  }
  const short *bsrc0, *bsrc1;
  {
    int p = tid >> 3, j = tid & 7, v = j ^ (p & 7);
    int r = 2 * p + (v >> 2), c = v & 3;
    bsrc0 = Pd + ((size_t)((e * 88 + 0) * 4 + c)) * (HD * 8) + (size_t)(n0 + r) * 8;
    bsrc1 = Pd + ((size_t)((e * 88 + 1) * 4 + c)) * (HD * 8) + (size_t)(n0 + r) * 8;
  }

  f32x16 acc = (f32x16)0.f;

  D_STAGE(0, 0); D_STAGE(1, 1); D_STAGE(2, 2);
  WAITV(8);
  BARRIER();

  for (int t = 0; t < 39; t += 3) {   // NTL = 44
    D_ITER(0, t);
    D_ITER(1, t + 1);
    D_ITER(2, t + 2);
  }
  D_ITER(0, 39);
  D_ITER(1, 40);
  D_COMPUTE(2);            // t=41
  WAITV(4); BARRIER();
  D_COMPUTE(0);            // t=42
  WAITV(0); BARRIER();
  D_COMPUTE(1);            // t=43

#pragma unroll
  for (int q = 0; q < 16; q++) {
    int r = row0 + wm * 32 + (q & 3) + 8 * (q >> 2) + 4 * l5;
    if (r < ne) {
      int slot = b0 + r;
      int tok = slot_token[slot];
      atomicAdd(&out[(size_t)tok * HD + n0 + wn * 32 + l31],
                acc[q] * slot_w[slot]);
    }
  }
}

extern "C" void kernel_launch(void* const* d_in, const int* in_sizes, int n_in,
                              void* d_out, int out_size, void* d_ws,
                              size_t ws_size, hipStream_t stream) {
  const float* x = (const float*)d_in[0];
  const float* rw = (const float*)d_in[1];
  const float* gw = (const float*)d_in[2];
  const float* uw = (const float*)d_in[3];
  const float* dw = (const float*)d_in[4];
  float* out = (float*)d_out;

  char* ws = (char*)d_ws;
  int* counts = (int*)(ws + 0);
  int* bases = (int*)(ws + 128);
  int* tok_i = (int*)(ws + 256);
  float* tok_w = (float*)(ws + 8448);
  int* slot_token = (int*)(ws + 16640);
  float* slot_w = (float*)(ws + 24832);
  short* xg = (short*)(ws + 41216);           // 2048 x 1024 bf16     (4.19 MB)
  short* m  = (short*)(ws + 4235520);         // 2048 x 2816 bf16     (11.5 MB)
  short* Pg = (short*)(ws + 15769856);        // gate panels          (46.1 MB)
  short* Pu = (short*)(ws + 61907200);        // up panels            (46.1 MB)
  short* PdBig = (short*)(ws + 108044544);    // down panels          (46.1 MB)
  const bool big = ws_size >= (size_t)108044544 + 46137344;
  short* Pd = big ? PdBig : Pg;

  (void)hipMemsetAsync(counts, 0, 64, stream);
  (void)hipMemsetAsync(out, 0, (size_t)out_size * 4, stream);
  router_kernel<<<NT, 64, 0, stream>>>(x, rw, counts, tok_i, tok_w);
  scanfill_kernel<<<1, 1024, 0, stream>>>(counts, tok_i, tok_w, bases,
                                          slot_token, slot_w);
  // K3: pack gate+up panels ∪ gather activations (NT panel stores)
  pack_gu_gather_kernel<<<7680, 256, 0, stream>>>(gw, uw, Pg, Pu, x,
                                                  slot_token, xg);
  // K4: gate/up GEMM (+silu) with pack-down blocks appended after
  if (big) {
    gemm_gu_packd_kernel<<<5632 + 2816, 256, 0, stream>>>(
        xg, Pg, Pu, bases, m, dw, Pd, 5632);
  } else {
    gemm_gu_packd_kernel<<<5632, 256, 0, stream>>>(xg, Pg, Pu, bases, m, dw,
                                                   Pd, 5632);
    gemm_gu_packd_kernel<<<2816, 256, 0, stream>>>(xg, Pg, Pu, bases, m, dw,
                                                   Pd, 0);
  }
  // K5: down GEMM, atomic combine into out
  down_kernel<<<dim3(128, 32), 256, 0, stream>>>(m, Pd, bases, slot_w,
                                                 slot_token, out);
}

// Round 21
// 199.253 us; speedup vs baseline: 1.0711x; 1.0711x over previous
//
#include <hip/hip_runtime.h>

#define HD 1024
#define FD 2816
#define NE 8
#define NT 1024
#define NSLOT (NT * 2)

typedef short short8 __attribute__((ext_vector_type(8)));
typedef unsigned u32x4 __attribute__((ext_vector_type(4)));
typedef unsigned u32x2 __attribute__((ext_vector_type(2)));
typedef float f32x4 __attribute__((ext_vector_type(4)));
typedef float f32x16 __attribute__((ext_vector_type(16)));

typedef __attribute__((address_space(3))) unsigned lds_u32;
typedef __attribute__((address_space(1))) const unsigned glb_u32;

#define WAITV(N) asm volatile("s_waitcnt vmcnt(" #N ") lgkmcnt(0)" ::: "memory")
#define BARRIER() do { __builtin_amdgcn_s_barrier(); __builtin_amdgcn_sched_barrier(0); } while (0)
#define SB() __builtin_amdgcn_sched_barrier(0)

__device__ __forceinline__ void glds16(const void* g, void* l) {
  __builtin_amdgcn_global_load_lds((glb_u32*)g, (lds_u32*)l, 16, 0, 0);
}

__device__ __forceinline__ short f2bf(float f) {
  unsigned u = __builtin_bit_cast(unsigned, f);
  u += 0x7FFFu + ((u >> 16) & 1u);   // round-to-nearest-even
  return (short)(u >> 16);
}
__device__ __forceinline__ unsigned cvtpk(float lo, float hi) {
  unsigned r;
  asm("v_cvt_pk_bf16_f32 %0, %1, %2" : "=v"(r) : "v"(lo), "v"(hi));
  return r;
}
__device__ __forceinline__ int imin(int a, int b) { return a < b ? a : b; }

// ---------------- router ----------------------------------------------------
__global__ void router_kernel(const float* __restrict__ x,
                              const float* __restrict__ rw,
                              int* __restrict__ counts,
                              int* __restrict__ tok_i,
                              float* __restrict__ tok_w) {
  const int t = blockIdx.x;
  const int lane = threadIdx.x;
  const float* px = x + (size_t)t * HD;
  float acc[NE];
#pragma unroll
  for (int e = 0; e < NE; e++) acc[e] = 0.f;
  for (int h = lane; h < HD; h += 64) {
    float xv = px[h];
#pragma unroll
    for (int e = 0; e < NE; e++) acc[e] += xv * rw[e * HD + h];
  }
#pragma unroll
  for (int e = 0; e < NE; e++) {
#pragma unroll
    for (int off = 32; off > 0; off >>= 1)
      acc[e] += __shfl_xor(acc[e], off, 64);
  }
  if (lane == 0) {
    float mx = acc[0];
#pragma unroll
    for (int e = 1; e < NE; e++) mx = fmaxf(mx, acc[e]);
    float ex[NE];
#pragma unroll
    for (int e = 0; e < NE; e++) ex[e] = __expf(acc[e] - mx);
    int i1 = 0;
#pragma unroll
    for (int e = 1; e < NE; e++) if (ex[e] > ex[i1]) i1 = e;
    int i2 = (i1 == 0) ? 1 : 0;
#pragma unroll
    for (int e = 0; e < NE; e++) if (e != i1 && ex[e] > ex[i2]) i2 = e;
    float inv = 1.f / (ex[i1] + ex[i2]);
    tok_i[t * 2 + 0] = i1; tok_w[t * 2 + 0] = ex[i1] * inv;
    tok_i[t * 2 + 1] = i2; tok_w[t * 2 + 1] = ex[i2] * inv;
    atomicAdd(&counts[i1], 1);
    atomicAdd(&counts[i2], 1);
  }
}

// ---------------- fused scan+fill (one block) -------------------------------
__global__ void scanfill_kernel(const int* __restrict__ counts,
                                const int* __restrict__ tok_i,
                                const float* __restrict__ tok_w,
                                int* __restrict__ bases,
                                int* __restrict__ slot_token,
                                float* __restrict__ slot_w) {
  __shared__ int cur[NE];
  const int t = threadIdx.x;
  if (t == 0) {
    int s = 0;
    for (int e = 0; e < NE; e++) { bases[e] = s; cur[e] = s; s += counts[e]; }
    bases[NE] = s;
  }
  __syncthreads();
#pragma unroll
  for (int k = 0; k < 2; k++) {
    int e = tok_i[t * 2 + k];
    int pos = atomicAdd(&cur[e], 1);
    slot_token[pos] = t;
    slot_w[pos] = tok_w[t * 2 + k];
  }
}

// ---------------- pack: coalesced stores via wave-local LDS bounce ----------
__device__ __forceinline__ void pack_block(const float* __restrict__ W,
                                           short* __restrict__ P, int K, int N,
                                           int f0, int kt, int e, int tid,
                                           char* smem) {
  const int KT = K >> 5;
  const int lane = tid & 63, w = tid >> 6;
  const float* src = W + (size_t)e * K * N + (size_t)(kt * 32 + w * 8) * N +
                     f0 + lane * 4;
  f32x4 x0 = *(const f32x4*)(src);
  f32x4 x1 = *(const f32x4*)(src + (size_t)N);
  f32x4 x2 = *(const f32x4*)(src + (size_t)2 * N);
  f32x4 x3 = *(const f32x4*)(src + (size_t)3 * N);
  f32x4 x4 = *(const f32x4*)(src + (size_t)4 * N);
  f32x4 x5 = *(const f32x4*)(src + (size_t)5 * N);
  f32x4 x6 = *(const f32x4*)(src + (size_t)6 * N);
  f32x4 x7 = *(const f32x4*)(src + (size_t)7 * N);
  unsigned* Lb = (unsigned*)(smem + w * 4608);
#pragma unroll
  for (int j = 0; j < 4; j++) {
    u32x4 c;
    c[0] = cvtpk(x0[j], x1[j]);
    c[1] = cvtpk(x2[j], x3[j]);
    c[2] = cvtpk(x4[j], x5[j]);
    c[3] = cvtpk(x6[j], x7[j]);
    int ch = 4 * lane + j;
    *(u32x4*)(Lb + (ch + (ch >> 3)) * 4) = c;
  }
  asm volatile("s_waitcnt lgkmcnt(0)" ::: "memory");
  SB();
  short* dstb = P + (((size_t)(e * KT + kt) * 4 + w) * N + f0) * 8;
#pragma unroll
  for (int j = 0; j < 4; j++) {
    int ch = j * 64 + lane;
    u32x4 c = *(const u32x4*)(Lb + (ch + (ch >> 3)) * 4);
    *(u32x4*)(dstb + (size_t)ch * 8) = c;
  }
}

// ---------------- K3: pack gate+up  UNION  gather ---------------------------
__global__ __launch_bounds__(256, 4) void pack_gu_gather_kernel(
    const float* __restrict__ gw, const float* __restrict__ uw,
    short* __restrict__ Pg, short* __restrict__ Pu,
    const float* __restrict__ x, const int* __restrict__ slot_token,
    short* __restrict__ xg) {
  __shared__ char smem[18432];
  const int bid = blockIdx.x;
  const int tid = threadIdx.x;
  if (bid < 5632) {   // 11 x 32 x 16 pack blocks
    const int f0 = (bid % 11) * 256;
    const int kt = (bid / 11) % 32;
    const int ez = bid / 352;
    pack_block(ez < NE ? gw : uw, ez < NE ? Pg : Pu, HD, FD, f0, kt, ez & 7,
               tid, smem);
  } else {            // 2048 gather blocks
    const int slot = bid - 5632;
    const int tok = slot_token[slot];
    f32x4 v = *(const f32x4*)(x + (size_t)tok * HD + tid * 4);
    u32x2 s;
    s[0] = cvtpk(v[0], v[1]);
    s[1] = cvtpk(v[2], v[3]);
    *(u32x2*)&xg[(size_t)slot * HD + tid * 4] = s;
  }
}

// ---------------- K4: fused gate+up GEMM  UNION  pack down ------------------

#define G_STAGE(S, T) do {                                           \
    glds16(asrc0 + (T) * 32, &As[S][wid * 512]);                     \
    glds16(asrc1 + (T) * 32, &As[S][2048 + wid * 512]);              \
    glds16(bgsrc + (size_t)(T) * 90112, &Bg[S][wid * 512]);          \
    glds16(busrc + (size_t)(T) * 90112, &Bu[S][wid * 512]);          \
  } while (0)

#define G_COMPUTE(S) do {                                                     \
    _Pragma("unroll")                                                         \
    for (int ks = 0; ks < 2; ks++) {                                          \
      const int oct = ks * 2 + l5;                                            \
      short8 a0, a1, bg, bu;                                                  \
      { int r = wm * 64 + l31, p = r >> 1;                                    \
        a0 = *(const short8*)&As[S][p * 64 +                                  \
              ((((r & 1) << 2) | oct) ^ (p & 7)) * 8]; }                      \
      { int r = wm * 64 + 32 + l31, p = r >> 1;                               \
        a1 = *(const short8*)&As[S][p * 64 +                                  \
              ((((r & 1) << 2) | oct) ^ (p & 7)) * 8]; }                      \
      { int n = wn * 32 + l31, pn = n >> 1;                                   \
        int off = pn * 64 + ((((n & 1) << 2) | oct) ^ (pn & 7)) * 8;          \
        bg = *(const short8*)&Bg[S][off];                                     \
        bu = *(const short8*)&Bu[S][off]; }                                   \
      accG0 = __builtin_amdgcn_mfma_f32_32x32x16_bf16(a0, bg, accG0, 0, 0, 0);\
      accU0 = __builtin_amdgcn_mfma_f32_32x32x16_bf16(a0, bu, accU0, 0, 0, 0);\
      accG1 = __builtin_amdgcn_mfma_f32_32x32x16_bf16(a1, bg, accG1, 0, 0, 0);\
      accU1 = __builtin_amdgcn_mfma_f32_32x32x16_bf16(a1, bu, accU1, 0, 0, 0);\
    }                                                                         \
  } while (0)

#define G_ITER(S, T) do {    \
    G_COMPUTE(S);            \
    BARRIER();               \
    G_STAGE(S, (T) + 3);     \
    WAITV(8);                \
    BARRIER();               \
  } while (0)

__global__ __launch_bounds__(256, 3) void gemm_gu_packd_kernel(
    const short* __restrict__ xg, const short* __restrict__ Pg,
    const short* __restrict__ Pu, const int* __restrict__ bases,
    short* __restrict__ m_out, const float* __restrict__ dwv,
    short* __restrict__ Pd, int gemmN) {
  __shared__ char smem[49152];
  const int bid = blockIdx.x;
  const int tid = threadIdx.x;

  if (bid >= gemmN) {   // pack-down blocks: 4 x 88 x 8 (single tile each)
    const int pid = bid - gemmN;
    const int f0 = (pid & 3) * 256;
    const int kt = (pid >> 2) % 88;
    const int e = pid / 352;
    pack_block(dwv, Pd, FD, HD, f0, kt, e, tid, smem);
    return;
  }

  const int gx = bid % 352;
  const int e = gx / 44, nt = gx - e * 44;
  const int b0 = bases[e];
  const int ne = bases[e + 1] - b0;
  const int row0 = (bid / 352) * 128;
  if (row0 >= ne) return;
  const int n0 = nt * 64;

  short (*As)[4096] = (short(*)[4096])smem;              // 3 x 8 KB
  short (*Bg)[2048] = (short(*)[2048])(smem + 24576);    // 3 x 4 KB
  short (*Bu)[2048] = (short(*)[2048])(smem + 36864);    // 3 x 4 KB

  const int lane = tid & 63, wid = tid >> 6;
  const int l31 = lane & 31, l5 = lane >> 5;
  const int wm = wid >> 1, wn = wid & 1;

  const short *asrc0, *asrc1;
  {
    int i = tid;
    int p = i >> 3, j = i & 7, v = j ^ (p & 7);
    int r = 2 * p + (v >> 2), c = v & 3;
    asrc0 = xg + (size_t)(b0 + imin(row0 + r, ne - 1)) * HD + c * 8;
    i = 256 + tid;
    p = i >> 3; j = i & 7; v = j ^ (p & 7);
    r = 2 * p + (v >> 2); c = v & 3;
    asrc1 = xg + (size_t)(b0 + imin(row0 + r, ne - 1)) * HD + c * 8;
  }
  const short *bgsrc, *busrc;
  {
    int p = tid >> 3, j = tid & 7, v = j ^ (p & 7);
    int r = 2 * p + (v >> 2), c = v & 3;
    size_t off = ((size_t)(e * 32 * 4 + c)) * (FD * 8) + (size_t)(n0 + r) * 8;
    bgsrc = Pg + off;
    busrc = Pu + off;
  }

  f32x16 accG0 = (f32x16)0.f, accG1 = (f32x16)0.f;
  f32x16 accU0 = (f32x16)0.f, accU1 = (f32x16)0.f;

  G_STAGE(0, 0); G_STAGE(1, 1); G_STAGE(2, 2);
  WAITV(8);
  BARRIER();

  for (int t = 0; t < 27; t += 3) {   // NTL = 32
    G_ITER(0, t);
    G_ITER(1, t + 1);
    G_ITER(2, t + 2);
  }
  G_ITER(0, 27);
  G_ITER(1, 28);
  G_COMPUTE(2);            // t=29
  WAITV(4); BARRIER();
  G_COMPUTE(0);            // t=30
  WAITV(0); BARRIER();
  G_COMPUTE(1);            // t=31

#pragma unroll
  for (int q = 0; q < 16; q++) {
    int rb_ = (q & 3) + 8 * (q >> 2) + 4 * l5;
    {
      int r = row0 + wm * 64 + rb_;
      if (r < ne) {
        float g = accG0[q], u = accU0[q];
        float mv = (g / (1.f + __expf(-g))) * u;
        m_out[(size_t)(b0 + r) * FD + n0 + wn * 32 + l31] = f2bf(mv);
      }
    }
    {
      int r = row0 + wm * 64 + 32 + rb_;
      if (r < ne) {
        float g = accG1[q], u = accU1[q];
        float mv = (g / (1.f + __expf(-g))) * u;
        m_out[(size_t)(b0 + r) * FD + n0 + wn * 32 + l31] = f2bf(mv);
      }
    }
  }
}

// ============ down grouped GEMM (BM=64 BN=64 BK=64, all-glds 3-deep) ========

#define D_STAGE(S, T) do {                                           \
    glds16(asrcA0 + (T) * 64, &As[S][wid * 512]);                    \
    glds16(asrcA1 + (T) * 64, &As[S][2048 + wid * 512]);             \
    glds16(bsrc0 + (size_t)(T) * 65536, &Bs[S][wid * 512]);          \
    glds16(bsrc1 + (size_t)(T) * 65536, &Bs[S][2048 + wid * 512]);   \
  } while (0)

#define D_COMPUTE(S) do {                                                     \
    _Pragma("unroll")                                                         \
    for (int ks = 0; ks < 4; ks++) {                                          \
      const int sub = ks >> 1, oct = (ks & 1) * 2 + l5;                       \
      short8 a, b;                                                            \
      { int r = wm * 32 + l31, p = r >> 1;                                    \
        a = *(const short8*)&As[S][sub * 2048 + p * 64 +                      \
              ((((r & 1) << 2) | oct) ^ (p & 7)) * 8]; }                      \
      { int n = wn * 32 + l31, pn = n >> 1;                                   \
        b = *(const short8*)&Bs[S][sub * 2048 + pn * 64 +                     \
              ((((n & 1) << 2) | oct) ^ (pn & 7)) * 8]; }                     \
      acc = __builtin_amdgcn_mfma_f32_32x32x16_bf16(a, b, acc, 0, 0, 0);      \
    }                                                                         \
  } while (0)

#define D_ITER(S, T) do {    \
    D_COMPUTE(S);            \
    BARRIER();               \
    D_STAGE(S, (T) + 3);     \
    WAITV(8);                \
    BARRIER();               \
  } while (0)

__global__ __launch_bounds__(256, 3) void down_kernel(
    const short* __restrict__ m_in, const short* __restrict__ Pd,
    const int* __restrict__ bases, const float* __restrict__ slot_w,
    const int* __restrict__ slot_token, float* __restrict__ out) {
  const int bx = blockIdx.x;
  const int e = bx >> 4, nt = bx & 15;
  const int b0 = bases[e];
  const int ne = bases[e + 1] - b0;
  const int row0 = blockIdx.y * 64;
  if (row0 >= ne) return;
  const int n0 = nt * 64;

  __shared__ short As[3][4096];
  __shared__ short Bs[3][4096];

  const int tid = threadIdx.x;
  const int lane = tid & 63, wid = tid >> 6;
  const int l31 = lane & 31, l5 = lane >> 5;
  const int wm = wid >> 1, wn = wid & 1;

  const short *asrcA0, *asrcA1;
  {
    int p = tid >> 3, j = tid & 7, v = j ^ (p & 7);
    int r = 2 * p + (v >> 2), c = v & 3;
    const short* base = m_in + (size_t)(b0 + imin(row0 + r, ne - 1)) * FD;
    asrcA0 = base + c * 8;
    asrcA1 = base + 32 + c * 8;
  }
  const short *bsrc0, *bsrc1;
  {
    int p = tid >> 3, j = tid & 7, v = j ^ (p & 7);
    int r = 2 * p + (v >> 2), c = v & 3;
    bsrc0 = Pd + ((size_t)((e * 88 + 0) * 4 + c)) * (HD * 8) + (size_t)(n0 + r) * 8;
    bsrc1 = Pd + ((size_t)((e * 88 + 1) * 4 + c)) * (HD * 8) + (size_t)(n0 + r) * 8;
  }

  f32x16 acc = (f32x16)0.f;

  D_STAGE(0, 0); D_STAGE(1, 1); D_STAGE(2, 2);
  WAITV(8);
  BARRIER();

  for (int t = 0; t < 39; t += 3) {   // NTL = 44
    D_ITER(0, t);
    D_ITER(1, t + 1);
    D_ITER(2, t + 2);
  }
  D_ITER(0, 39);
  D_ITER(1, 40);
  D_COMPUTE(2);            // t=41
  WAITV(4); BARRIER();
  D_COMPUTE(0);            // t=42
  WAITV(0); BARRIER();
  D_COMPUTE(1);            // t=43

#pragma unroll
  for (int q = 0; q < 16; q++) {
    int r = row0 + wm * 32 + (q & 3) + 8 * (q >> 2) + 4 * l5;
    if (r < ne) {
      int slot = b0 + r;
      int tok = slot_token[slot];
      atomicAdd(&out[(size_t)tok * HD + n0 + wn * 32 + l31],
                acc[q] * slot_w[slot]);
    }
  }
}

extern "C" void kernel_launch(void* const* d_in, const int* in_sizes, int n_in,
                              void* d_out, int out_size, void* d_ws,
                              size_t ws_size, hipStream_t stream) {
  const float* x = (const float*)d_in[0];
  const float* rw = (const float*)d_in[1];
  const float* gw = (const float*)d_in[2];
  const float* uw = (const float*)d_in[3];
  const float* dw = (const float*)d_in[4];
  float* out = (float*)d_out;

  char* ws = (char*)d_ws;
  int* counts = (int*)(ws + 0);
  int* bases = (int*)(ws + 128);
  int* tok_i = (int*)(ws + 256);
  float* tok_w = (float*)(ws + 8448);
  int* slot_token = (int*)(ws + 16640);
  float* slot_w = (float*)(ws + 24832);
  short* xg = (short*)(ws + 41216);           // 2048 x 1024 bf16     (4.19 MB)
  short* m  = (short*)(ws + 4235520);         // 2048 x 2816 bf16     (11.5 MB)
  short* Pg = (short*)(ws + 15769856);        // gate panels          (46.1 MB)
  short* Pu = (short*)(ws + 61907200);        // up panels            (46.1 MB)
  short* PdBig = (short*)(ws + 108044544);    // down panels          (46.1 MB)
  const bool big = ws_size >= (size_t)108044544 + 46137344;
  short* Pd = big ? PdBig : Pg;

  (void)hipMemsetAsync(counts, 0, 64, stream);
  (void)hipMemsetAsync(out, 0, (size_t)out_size * 4, stream);
  router_kernel<<<NT, 64, 0, stream>>>(x, rw, counts, tok_i, tok_w);
  scanfill_kernel<<<1, 1024, 0, stream>>>(counts, tok_i, tok_w, bases,
                                          slot_token, slot_w);
  // K3: pack gate+up panels ∪ gather activations
  pack_gu_gather_kernel<<<7680, 256, 0, stream>>>(gw, uw, Pg, Pu, x,
                                                  slot_token, xg);
  // K4: gate/up GEMM (+silu) with pack-down blocks appended after
  if (big) {
    gemm_gu_packd_kernel<<<5632 + 2816, 256, 0, stream>>>(
        xg, Pg, Pu, bases, m, dw, Pd, 5632);
  } else {
    gemm_gu_packd_kernel<<<5632, 256, 0, stream>>>(xg, Pg, Pu, bases, m, dw,
                                                   Pd, 5632);
    gemm_gu_packd_kernel<<<2816, 256, 0, stream>>>(xg, Pg, Pu, bases, m, dw,
                                                   Pd, 0);
  }
  // K5: down GEMM, atomic combine into out
  down_kernel<<<dim3(128, 32), 256, 0, stream>>>(m, Pd, bases, slot_w,
                                                 slot_token, out);
}